// Round 14
// baseline (734.406 us; speedup 1.0000x reference)
//
#include <hip/hip_runtime.h>
#include <math.h>
#include <stdint.h>

#define BATCH 64
#define T 256
#define NF 64
#define H 128
#define H4 512                    // 4*H
#define HP1 129
#define WF_STRIDE (HP1 * H4)      // 66048 floats per feature
#define FEATS (NF * H + H)        // 8320
#define NTH 1024                  // 16 waves: 2 halves x 8 waves (one batch each)

// pack7: uint4 idx = (f*8 + u)*512 + t ; u = g*2+q, t: kq=t>>7, cg=t&127.
// dword w byte r <-> k = kq*32 + q*16 + 4w + r, col = g*128 + cg,
// val = fp8_e4m3(W_lin[f][1+k][col] * 4096)
#define PACK7_U4 (NF * 8 * 512)
#define PACK7_BYTES ((size_t)PACK7_U4 * 16u)          // 4 MB
// aux7: float4 idx = f*512 + t : kq==0 -> wx[4 cols], kq==1 -> bias[4 cols], else 0
#define AUX7_BYTES ((size_t)NF * 512 * 16u)           // 512 KB
#define WS_NEED (PACK7_BYTES + AUX7_BYTES)

typedef float vf2 __attribute__((ext_vector_type(2)));

__device__ __forceinline__ float sigmoidf_(float x) {
    return 1.0f / (1.0f + __expf(-x));
}

__device__ __forceinline__ float tanhf_(float x) {
    float ax = fabsf(x);
    float e = __expf(2.0f * ax);              // inf for large ax -> r = 1
    float r = 1.0f - 2.0f / (e + 1.0f);
    return copysignf(r, x);
}

// decode 2 fp8 bytes of a dword -> float2 (HI must be literal)
template<bool HI>
__device__ __forceinline__ vf2 dec2f(unsigned u) {
    return __builtin_amdgcn_cvt_pk_f32_fp8(u, HI);
}

// ===== repack7: fp8 x4096, 512-thread-half layout ===========================
__global__ __launch_bounds__(256)
void repack7_kernel(const float* __restrict__ W_lin, uint4* __restrict__ pack) {
    const int lin = blockIdx.x * 256 + threadIdx.x;   // 0..262143
    const int t   = lin & 511;
    const int u   = (lin >> 9) & 7;
    const int f   = lin >> 12;
    const int g   = u >> 1;
    const int q   = u & 1;
    const int kq  = t >> 7;
    const int cg  = t & 127;
    const int col = g * 128 + cg;
    const int k0  = kq * 32 + q * 16;
    unsigned uw[4];
    #pragma unroll
    for (int w = 0; w < 4; ++w) {
        const float* src = W_lin + (size_t)f * WF_STRIDE
                         + (size_t)(1 + k0 + 4 * w) * H4 + col;
        const float v0 = src[0]      * 4096.0f;
        const float v1 = src[H4]     * 4096.0f;
        const float v2 = src[2 * H4] * 4096.0f;
        const float v3 = src[3 * H4] * 4096.0f;
        unsigned r = 0;
        r = __builtin_amdgcn_cvt_pk_fp8_f32(v0, v1, r, false);
        r = __builtin_amdgcn_cvt_pk_fp8_f32(v2, v3, r, true);
        uw[w] = r;
    }
    uint4 o; o.x = uw[0]; o.y = uw[1]; o.z = uw[2]; o.w = uw[3];
    pack[lin] = o;
}

// aux7[f*512 + t]: kq==0 -> x-row for cols {g*128+cg}, kq==1 -> bias, else 0
__global__ __launch_bounds__(256)
void aux7_kernel(const float* __restrict__ W_lin, const float* __restrict__ b_lin,
                 float4* __restrict__ aux) {
    const int lin = blockIdx.x * 256 + threadIdx.x;   // 0..32767
    const int t   = lin & 511;
    const int f   = lin >> 9;
    const int kq  = t >> 7;
    const int cg  = t & 127;
    float4 o = make_float4(0.f, 0.f, 0.f, 0.f);
    if (kq == 0) {
        o.x = W_lin[(size_t)f * WF_STRIDE + cg];
        o.y = W_lin[(size_t)f * WF_STRIDE + 128 + cg];
        o.z = W_lin[(size_t)f * WF_STRIDE + 256 + cg];
        o.w = W_lin[(size_t)f * WF_STRIDE + 384 + cg];
    } else if (kq == 1) {
        o.x = b_lin[f * H4 + cg];
        o.y = b_lin[f * H4 + 128 + cg];
        o.z = b_lin[f * H4 + 256 + cg];
        o.w = b_lin[f * H4 + 384 + cg];
    }
    aux[lin] = o;
}

// ===== main scan: 2 independent batches per block ===========================
// Waves 0-7 run batch A's step, waves 8-15 batch B's, sharing the two
// barriers: one serial-chain traversal (the measured ~3500cy invariant)
// completes TWO sequence-steps. No cross-sequence coupling (unlike R9's
// same-sequence pairing): no collisions, no extra barriers. Matvec/gate
// math verbatim R13 (absmax-0-verified), 4-way K-split per 512-thread half.
__global__ __launch_bounds__(NTH, 1)
void lstm_scan_fp8_v5(const float* __restrict__ X,
                      const int* __restrict__ lengths,
                      const float* __restrict__ W_dec,
                      const float* __restrict__ b_dec,
                      const float* __restrict__ W_out,
                      const float* __restrict__ b_out,
                      const uint4* __restrict__ pack,
                      const float4* __restrict__ aux,
                      float* __restrict__ out)
{
    __shared__ float s_ht[2][NF * H];         // 64 KB: per-batch h tables
    __shared__ float s_inp[2][H];             // decayed hidden rows
    __shared__ float s_part[2][4][H4];        // per-batch 4-way K partials (16 KB)
    __shared__ float s_X[2][4 * T];           // 8 KB
    __shared__ float s_wdec[NF];
    __shared__ float s_bdec[NF];
    __shared__ float s_cfin[2][H];
    __shared__ float s_red[32];

    const int tid  = threadIdx.x;
    const int blk  = blockIdx.x;              // 0..31
    const int half = tid >> 9;                // 0: batch A, 1: batch B
    const int t    = tid & 511;
    const int cg   = t & 127;                 // column within gate
    const int kq   = t >> 7;                  // K chunk 0..3 (wave-uniform)

    const int bA = blk, bB = blk + 32;
    const int myB = half ? bB : bA;

    const int lenA = lengths[bA];
    const int lenB = lengths[bB];
    const int myLen = half ? lenB : lenA;
    const int lenM = (lenA > lenB) ? lenA : lenB;

    for (int i = tid; i < 4 * T; i += NTH) {
        s_X[0][i] = X[bA * 4 * T + i];
        s_X[1][i] = X[bB * 4 * T + i];
    }
    for (int i = tid; i < NF * H; i += NTH) { s_ht[0][i] = 0.0f; s_ht[1][i] = 0.0f; }
    if (tid < NF) { s_wdec[tid] = W_dec[tid]; s_bdec[tid] = b_dec[tid]; }
    if (tid < H) { s_inp[0][tid] = 0.0f; s_inp[1][tid] = 0.0f; }
    __syncthreads();

    const float* myX = s_X[half];

    float c_t = 0.0f, accs = 0.0f, cnts = 0.0f;

    // one gate: two uint4 (32 fp8 k's) vs iv[0..15] (32 f32 as 16 vf2)
    #define DOT2(WA, WB, OUTV) do {                                             \
        vf2 ac; ac[0] = 0.0f; ac[1] = 0.0f;                                     \
        vf2 d;                                                                  \
        d = dec2f<false>((WA).x); ac += d * iv[0];                              \
        d = dec2f<true >((WA).x); ac += d * iv[1];                              \
        d = dec2f<false>((WA).y); ac += d * iv[2];                              \
        d = dec2f<true >((WA).y); ac += d * iv[3];                              \
        d = dec2f<false>((WA).z); ac += d * iv[4];                              \
        d = dec2f<true >((WA).z); ac += d * iv[5];                              \
        d = dec2f<false>((WA).w); ac += d * iv[6];                              \
        d = dec2f<true >((WA).w); ac += d * iv[7];                              \
        d = dec2f<false>((WB).x); ac += d * iv[8];                              \
        d = dec2f<true >((WB).x); ac += d * iv[9];                              \
        d = dec2f<false>((WB).y); ac += d * iv[10];                             \
        d = dec2f<true >((WB).y); ac += d * iv[11];                             \
        d = dec2f<false>((WB).z); ac += d * iv[12];                             \
        d = dec2f<true >((WB).z); ac += d * iv[13];                             \
        d = dec2f<false>((WB).w); ac += d * iv[14];                             \
        d = dec2f<true >((WB).w); ac += d * iv[15];                             \
        OUTV = (ac[0] + ac[1]) * (1.0f / 4096.0f);                              \
    } while (0)

    uint4 A0, A1, A2, A3, A4, A5, A6, A7;
    uint4 B0, B1, B2, B3, B4, B5, B6, B7;
    float4 AX = make_float4(0.f, 0.f, 0.f, 0.f), BX = AX;

    // prologue: prefetch step 0 of own batch
    {
        const int m0 = (int)myX[T];
        const uint4* p0 = pack + (size_t)m0 * 4096 + t;
        A0 = p0[0];    A1 = p0[512];  A2 = p0[1024]; A3 = p0[1536];
        A4 = p0[2048]; A5 = p0[2560]; A6 = p0[3072]; A7 = p0[3584];
        AX = aux[(size_t)m0 * 512 + t];
    }

    #define STEP(C0,C1,C2,C3,C4,C5,C6,C7,CX, N0,N1,N2,N3,N4,N5,N6,N7,NX)        \
    {                                                                           \
        const int   mj  = (int)myX[T + j];                                      \
        const float xj  = myX[2 * T + j];                                       \
        const int   jn  = (j + 1 < T) ? (j + 1) : (T - 1);                      \
        const int   mjn = (int)myX[T + jn];                                     \
        /* prefetch next step (consumed NEXT iteration) */                      \
        {                                                                       \
            const uint4* pn = pack + (size_t)mjn * 4096 + t;                    \
            N0 = pn[0];    N1 = pn[512];  N2 = pn[1024]; N3 = pn[1536];         \
            N4 = pn[2048]; N5 = pn[2560]; N6 = pn[3072]; N7 = pn[3584];         \
            NX = aux[(size_t)mjn * 512 + t];                                    \
        }                                                                       \
        /* input slice: 32 f32 (8 b128, wave-uniform addr -> broadcast) */      \
        vf2 iv[16];                                                             \
        {                                                                       \
            const float4* ip = (const float4*)(s_inp[half] + kq * 32);          \
            _Pragma("unroll")                                                   \
            for (int q = 0; q < 8; ++q) {                                       \
                const float4 t_ = ip[q];                                        \
                iv[2 * q][0] = t_.x;     iv[2 * q][1] = t_.y;                   \
                iv[2 * q + 1][0] = t_.z; iv[2 * q + 1][1] = t_.w;               \
            }                                                                   \
        }                                                                       \
        float a0, a1, a2, a3;                                                   \
        DOT2(C0, C1, a0); DOT2(C2, C3, a1); DOT2(C4, C5, a2); DOT2(C6, C7, a3); \
        if (kq == 0) {                                                          \
            a0 = fmaf(xj, CX.x, a0); a1 = fmaf(xj, CX.y, a1);                   \
            a2 = fmaf(xj, CX.z, a2); a3 = fmaf(xj, CX.w, a3);                   \
        } else if (kq == 1) {                                                   \
            a0 += CX.x; a1 += CX.y; a2 += CX.z; a3 += CX.w;                     \
        }                                                                       \
        s_part[half][kq][cg]       = a0;                                        \
        s_part[half][kq][128 + cg] = a1;                                        \
        s_part[half][kq][256 + cg] = a2;                                        \
        s_part[half][kq][384 + cg] = a3;                                        \
        __syncthreads();  /* B: partials ready */                               \
        if (t < H && j < myLen) {                                               \
            const int h = t;                                                    \
            float g0 = 0.f, g1 = 0.f, g2 = 0.f, g3 = 0.f;                       \
            _Pragma("unroll")                                                   \
            for (int q = 0; q < 4; ++q) {                                       \
                g0 += s_part[half][q][h];                                       \
                g1 += s_part[half][q][128 + h];                                 \
                g2 += s_part[half][q][256 + h];                                 \
                g3 += s_part[half][q][384 + h];                                 \
            }                                                                   \
            const float c_cand = sigmoidf_(g1) * c_t + sigmoidf_(g0) * tanhf_(g3); \
            const float h_row  = sigmoidf_(g2) * tanhf_(c_cand);                \
            s_ht[half][mj * H + h] = h_row;                                     \
            accs += c_cand;                                                     \
            cnts += 1.0f;                                                       \
            const float tj = myX[j];                                            \
            const float tn = (j < T - 1) ? myX[j + 1] : (tj + 1.0f);            \
            const bool boundary = (j == myLen - 1) || (tn != tj);               \
            if (boundary) { c_t = accs / fmaxf(cnts, 1.0f); accs = 0.0f; cnts = 0.0f; } \
            const float dn  = myX[3 * T + jn];                                  \
            const float dmn = fmaf(s_wdec[mjn], dn, s_bdec[mjn]);               \
            const float den = __expf(-fmaxf(0.0f, dmn));                        \
            const float hv  = (mjn == mj) ? h_row : s_ht[half][mjn * H + h];    \
            s_inp[half][h] = den * hv;                                          \
        }                                                                       \
        __syncthreads();  /* A: s_inp + h_t ready */                            \
    }

    int j = 0;
    while (j < lenM) {
        STEP(A0,A1,A2,A3,A4,A5,A6,A7,AX, B0,B1,B2,B3,B4,B5,B6,B7,BX); ++j;
        if (j >= lenM) break;
        STEP(B0,B1,B2,B3,B4,B5,B6,B7,BX, A0,A1,A2,A3,A4,A5,A6,A7,AX); ++j;
    }
    #undef STEP
    #undef DOT2

    // ---- epilogue: each half reduces its own batch ----
    if (t < H) s_cfin[half][t] = c_t;
    __syncthreads();

    float z0 = 0.0f, z1 = 0.0f;
    for (int i = t; i < FEATS; i += 512) {
        const float f = (i < H) ? s_cfin[half][i] : s_ht[half][i - H];
        const float2 w = *(const float2*)(W_out + 2 * i);
        z0 = fmaf(f, w.x, z0);
        z1 = fmaf(f, w.y, z1);
    }
    #pragma unroll
    for (int off = 32; off > 0; off >>= 1) {
        z0 += __shfl_down(z0, off, 64);
        z1 += __shfl_down(z1, off, 64);
    }
    const int wave = tid >> 6, lane = tid & 63;
    if (lane == 0) { s_red[2 * wave] = z0; s_red[2 * wave + 1] = z1; }
    __syncthreads();
    if (t == 0) {
        const int w0 = half * 8;
        float a0 = b_out[0], a1 = b_out[1];
        #pragma unroll
        for (int w = 0; w < 8; ++w) { a0 += s_red[2 * (w0 + w)]; a1 += s_red[2 * (w0 + w) + 1]; }
        const float mx = fmaxf(a0, a1);
        const float e0 = __expf(a0 - mx), e1 = __expf(a1 - mx);
        const float inv = 1.0f / (e0 + e1);
        out[2 * myB]     = e0 * inv;
        out[2 * myB + 1] = e1 * inv;
    }
}

// ---------------- fp32 fallback (no-workspace path) ----------------
#define NTHREADS 512
__global__ __launch_bounds__(NTHREADS)
void lstm_scan_kernel(const float* __restrict__ X,
                      const int* __restrict__ lengths,
                      const float* __restrict__ W_lin,
                      const float* __restrict__ b_lin,
                      const float* __restrict__ W_dec,
                      const float* __restrict__ b_dec,
                      const float* __restrict__ W_out,
                      const float* __restrict__ b_out,
                      float* __restrict__ out)
{
    __shared__ float s_feats[FEATS];
    __shared__ float s_inp[H];
    __shared__ float s_part[4][H4];
    __shared__ float s_X[4 * T];
    __shared__ float s_wdec[NF];
    __shared__ float s_bdec[NF];
    __shared__ float s_red[16];

    float* s_ct = s_feats;
    float* s_ht = s_feats + H;

    const int tid = threadIdx.x;
    const int b   = blockIdx.x;
    const int g4  = tid & 127;
    const int kq  = tid >> 7;

    const float* Xb = X + b * 4 * T;
    const int len = lengths[b];

    for (int i = tid; i < NF * H; i += NTHREADS) s_ht[i] = 0.0f;
    for (int i = tid; i < 4 * T; i += NTHREADS) s_X[i] = Xb[i];
    if (tid < NF) { s_wdec[tid] = W_dec[tid]; s_bdec[tid] = b_dec[tid]; }
    __syncthreads();

    float c_t = 0.0f, acc = 0.0f, cnt = 0.0f;

    for (int j = 0; j < len; ++j) {
        const int   mj = (int)s_X[T + j];
        const float xj = s_X[2 * T + j];
        const float* Wf = W_lin + mj * WF_STRIDE;

        float bl0, bl1, bl2, bl3;
        if (tid < H) {
            const float dj    = s_X[3 * T + j];
            const float dm    = fmaf(s_wdec[mj], dj, s_bdec[mj]);
            const float decay = __expf(-fmaxf(0.0f, dm));
            s_inp[tid] = decay * s_ht[mj * H + tid];
            const int m4 = mj * H4;
            bl0 = b_lin[m4 + tid];
            bl1 = b_lin[m4 + H + tid];
            bl2 = b_lin[m4 + 2 * H + tid];
            bl3 = b_lin[m4 + 3 * H + tid];
        }
        __syncthreads();

        float4 a4 = make_float4(0.0f, 0.0f, 0.0f, 0.0f);
        {
            const float*  wr  = Wf + (1 + kq * 32) * H4 + 4 * g4;
            const float4* ivp = (const float4*)(s_inp + kq * 32);
            #pragma unroll
            for (int cc = 0; cc < 8; ++cc) {
                const float4 v = ivp[cc];
                const float* wrc = wr + (4 * cc) * H4;
                const float4 w0 = *(const float4*)(wrc);
                const float4 w1 = *(const float4*)(wrc + H4);
                const float4 w2 = *(const float4*)(wrc + 2 * H4);
                const float4 w3 = *(const float4*)(wrc + 3 * H4);
                a4.x = fmaf(v.x, w0.x, a4.x); a4.y = fmaf(v.x, w0.y, a4.y);
                a4.z = fmaf(v.x, w0.z, a4.z); a4.w = fmaf(v.x, w0.w, a4.w);
                a4.x = fmaf(v.y, w1.x, a4.x); a4.y = fmaf(v.y, w1.y, a4.y);
                a4.z = fmaf(v.y, w1.z, a4.z); a4.w = fmaf(v.y, w1.w, a4.w);
                a4.x = fmaf(v.z, w2.x, a4.x); a4.y = fmaf(v.z, w2.y, a4.y);
                a4.z = fmaf(v.z, w2.z, a4.z); a4.w = fmaf(v.z, w2.w, a4.w);
                a4.x = fmaf(v.w, w3.x, a4.x); a4.y = fmaf(v.w, w3.y, a4.y);
                a4.z = fmaf(v.w, w3.z, a4.z); a4.w = fmaf(v.w, w3.w, a4.w);
            }
        }
        if (kq == 0) {
            const float4 wv = *(const float4*)(Wf + 4 * g4);
            a4.x = fmaf(xj, wv.x, a4.x); a4.y = fmaf(xj, wv.y, a4.y);
            a4.z = fmaf(xj, wv.z, a4.z); a4.w = fmaf(xj, wv.w, a4.w);
        }
        *(float4*)(&s_part[kq][4 * g4]) = a4;
        __syncthreads();

        if (tid < H) {
            const int h = tid;
            const float gi = s_part[0][h]         + s_part[1][h]         + s_part[2][h]         + s_part[3][h]         + bl0;
            const float gf = s_part[0][H + h]     + s_part[1][H + h]     + s_part[2][H + h]     + s_part[3][H + h]     + bl1;
            const float go = s_part[0][2*H + h]   + s_part[1][2*H + h]   + s_part[2][2*H + h]   + s_part[3][2*H + h]   + bl2;
            const float gc = s_part[0][3*H + h]   + s_part[1][3*H + h]   + s_part[2][3*H + h]   + s_part[3][3*H + h]   + bl3;

            const float c_cand = sigmoidf_(gf) * c_t + sigmoidf_(gi) * tanhf_(gc);
            const float h_row  = sigmoidf_(go) * tanhf_(c_cand);
            s_ht[mj * H + h] = h_row;
            acc += c_cand;
            cnt += 1.0f;

            const float tj = s_X[j];
            const float tn = (j < T - 1) ? s_X[j + 1] : (tj + 1.0f);
            const bool boundary = (j == len - 1) || (tn != tj);
            if (boundary) { c_t = acc / fmaxf(cnt, 1.0f); acc = 0.0f; cnt = 0.0f; }
        }
        __syncthreads();
    }

    if (tid < H) s_ct[tid] = c_t;
    __syncthreads();

    float z0 = 0.0f, z1 = 0.0f;
    for (int i = tid; i < FEATS; i += NTHREADS) {
        const float f = s_feats[i];
        const float2 wv = *(const float2*)(W_out + 2 * i);
        z0 = fmaf(f, wv.x, z0);
        z1 = fmaf(f, wv.y, z1);
    }
    #pragma unroll
    for (int off = 32; off > 0; off >>= 1) {
        z0 += __shfl_down(z0, off, 64);
        z1 += __shfl_down(z1, off, 64);
    }
    const int wave = tid >> 6, lane = tid & 63;
    if (lane == 0) { s_red[2 * wave] = z0; s_red[2 * wave + 1] = z1; }
    __syncthreads();
    if (tid == 0) {
        float a0 = b_out[0], a1 = b_out[1];
        #pragma unroll
        for (int q = 0; q < 8; ++q) { a0 += s_red[2 * q]; a1 += s_red[2 * q + 1]; }
        const float mx = fmaxf(a0, a1);
        const float e0 = __expf(a0 - mx), e1 = __expf(a1 - mx);
        const float inv = 1.0f / (e0 + e1);
        out[2 * b]     = e0 * inv;
        out[2 * b + 1] = e1 * inv;
    }
}

extern "C" void kernel_launch(void* const* d_in, const int* in_sizes, int n_in,
                              void* d_out, int out_size, void* d_ws, size_t ws_size,
                              hipStream_t stream) {
    const float* X      = (const float*)d_in[0];
    const int*   lens   = (const int*)d_in[1];
    const float* W_lin  = (const float*)d_in[2];
    const float* b_lin  = (const float*)d_in[3];
    const float* W_dec  = (const float*)d_in[4];
    const float* b_dec  = (const float*)d_in[5];
    const float* W_out  = (const float*)d_in[6];
    const float* b_out  = (const float*)d_in[7];
    float* out = (float*)d_out;

    if (ws_size >= WS_NEED) {
        uint4*  pack = (uint4*)d_ws;
        float4* aux  = (float4*)((char*)d_ws + PACK7_BYTES);
        hipLaunchKernelGGL(repack7_kernel, dim3(PACK7_U4 / 256), dim3(256), 0, stream,
                           W_lin, pack);
        hipLaunchKernelGGL(aux7_kernel, dim3(NF * 512 / 256), dim3(256), 0, stream,
                           W_lin, b_lin, aux);
        hipLaunchKernelGGL(lstm_scan_fp8_v5, dim3(BATCH / 2), dim3(NTH), 0, stream,
                           X, lens, W_dec, b_dec, W_out, b_out, pack, aux, out);
    } else {
        hipLaunchKernelGGL(lstm_scan_kernel, dim3(BATCH), dim3(NTHREADS), 0, stream,
                           X, lens, W_lin, b_lin, W_dec, b_dec, W_out, b_out, out);
    }
}